// Round 1
// baseline (3426.751 us; speedup 1.0000x reference)
//
#include <hip/hip_runtime.h>
#include <hip/hip_bf16.h>
#include <math.h>

// Problem constants (from reference)
#define T_TOK 8192
#define HDIM  2048
#define NEXP  32
#define KTOP  8
#define IDIM  1024
#define NSHI  2048     // NSH * I
#define SCALE_F 2.5f

typedef _Float16 f16;
typedef __attribute__((ext_vector_type(8))) _Float16 f16x8;
typedef __attribute__((ext_vector_type(4))) float f32x4;

// ---------------- async global->LDS 16B ----------------
__device__ __forceinline__ void g2l16(const void* gc, void* l) {
  void* g = const_cast<void*>(gc);
  __builtin_amdgcn_global_load_lds((__attribute__((address_space(1))) void*)g,
                                   (__attribute__((address_space(3))) void*)l, 16, 0, 0);
}

// ---------------- tiny init ----------------
__global__ void k_zero(int* counts) {
  if (threadIdx.x < NEXP) counts[threadIdx.x] = 0;
}

// ---------------- fp32 -> f16 elementwise cast (8/thread) ----------------
__global__ void k_cast_f16(const float* __restrict__ s, f16* __restrict__ d, long n) {
  long i = ((long)blockIdx.x * 256 + threadIdx.x) * 8;
  if (i >= n) return;
  float4 a = *(const float4*)(s + i);
  float4 b = *(const float4*)(s + i + 4);
  f16x8 v = {(f16)a.x, (f16)a.y, (f16)a.z, (f16)a.w,
             (f16)b.x, (f16)b.y, (f16)b.z, (f16)b.w};
  *(f16x8*)(d + i) = v;
}

// ---------------- transpose + cast: src fp32 [R][C] -> dst f16 row c = src col c
// dst element (c, r) at dst[(c*rowStride + rowOff)*R + r]; batched over z ----------------
__global__ void k_tcast(const float* __restrict__ src, f16* __restrict__ dst,
                        int R, int C, long sBatch, long dBatch, int rowStride, int rowOff) {
  __shared__ float tile[32][33];
  const float* s = src + (long)blockIdx.z * sBatch;
  f16* d = dst + (long)blockIdx.z * dBatch;
  int c0 = blockIdx.x * 32, r0 = blockIdx.y * 32;
  int tx = threadIdx.x & 31, ty = threadIdx.x >> 5;
#pragma unroll
  for (int i = 0; i < 32; i += 8)
    tile[ty + i][tx] = s[(long)(r0 + ty + i) * C + (c0 + tx)];
  __syncthreads();
#pragma unroll
  for (int i = 0; i < 32; i += 8) {
    int c = c0 + ty + i;
    d[((long)c * rowStride + rowOff) * R + (r0 + tx)] = (f16)tile[tx][ty + i];
  }
}

// ---------------- router: logits (fp64 acc), sigmoid, biased top-8, bucket scatter ----------------
__global__ __launch_bounds__(256) void k_router(
    const float* __restrict__ x, const float* __restrict__ gw, const float* __restrict__ gb,
    int* __restrict__ counts, int* __restrict__ btok, float* __restrict__ bw,
    float* __restrict__ ids_out) {
  int e = threadIdx.x & 31;
  int tl = threadIdx.x >> 5;  // 0..7 tokens per block
  int t = blockIdx.x * 8 + tl;
  const float* xr = x + (long)t * HDIM;
  double a0 = 0, a1 = 0, a2 = 0, a3 = 0;
  for (int h = 0; h < HDIM; h += 4) {
    a0 += (double)xr[h + 0] * (double)gw[(h + 0) * NEXP + e];
    a1 += (double)xr[h + 1] * (double)gw[(h + 1) * NEXP + e];
    a2 += (double)xr[h + 2] * (double)gw[(h + 2) * NEXP + e];
    a3 += (double)xr[h + 3] * (double)gw[(h + 3) * NEXP + e];
  }
  float logit = (float)((a0 + a1) + (a2 + a3));
  float score = 1.0f / (1.0f + expf(-logit));
  float choice = score + gb[e];
  int ids[KTOP];
  float wk[KTOP];
  float wsum = 0.f;
#pragma unroll
  for (int k = 0; k < KTOP; ++k) {
    float v = choice;
    int id = e;
#pragma unroll
    for (int off = 16; off > 0; off >>= 1) {
      float ov = __shfl_xor(v, off, 32);
      int oid = __shfl_xor(id, off, 32);
      if (ov > v || (ov == v && oid < id)) { v = ov; id = oid; }
    }
    ids[k] = id;
    float s_ = __shfl(score, id, 32);
    wk[k] = s_;
    wsum += s_;
    if (e == id) choice = -INFINITY;
  }
  float inv = SCALE_F / (wsum + 1e-20f);
  if (e == 0) {
#pragma unroll
    for (int k = 0; k < KTOP; ++k) {
      int id = ids[k];
      int pos = atomicAdd(&counts[id], 1);
      btok[id * T_TOK + pos] = t;
      bw[id * T_TOK + pos] = wk[k] * inv;
      ids_out[t * KTOP + k] = (float)id;
    }
  }
}

__global__ void k_prefix(const int* __restrict__ counts, int* __restrict__ offsets) {
  if (threadIdx.x == 0) {
    int s = 0;
    for (int e = 0; e < NEXP; ++e) { offsets[e] = s; s += counts[e]; }
    offsets[NEXP] = s;
  }
}

// ---------------- unified 128x128x32 MFMA GEMM ----------------
// MODE 0: shared GEMM1  (A=xb identity rows, dual interleaved B, silu*up -> f16 out)
// MODE 1: expert GEMM1  (A=xb gathered rows via btok, dual B, f16 out at offsets[e]+m)
// MODE 2: shared GEMM2  (A=shb identity, single B, plain fp32 store)
// MODE 3: expert GEMM2  (A=hb rows offsets[e]+m, single B, weighted atomicAdd to out)
template <int MODE>
__global__ __launch_bounds__(256, 2) void k_gemm(
    const f16* __restrict__ A, const f16* __restrict__ B,
    float* __restrict__ outF, f16* __restrict__ outB,
    const int* __restrict__ counts, const int* __restrict__ offsets,
    const int* __restrict__ btok, const float* __restrict__ bw,
    int Mfixed, int Kd, int NbTot, int NoutCols, int TotalRows) {
  constexpr bool DUAL = (MODE < 2);
  constexpr bool EXP = (MODE == 1 || MODE == 3);
  __shared__ f16 As[128 * 32];
  __shared__ f16 Bs[128 * 32];
  __shared__ int stok[128];
  __shared__ float swt[128];

  int e = blockIdx.z;
  int M = EXP ? counts[e] : Mfixed;
  int m0 = blockIdx.x * 128;
  if (m0 >= M) return;
  int rowbase = EXP ? offsets[e] : 0;
  int n0 = blockIdx.y * 128;
  const f16* Bp = B + (long)e * NbTot * Kd;

  int t = threadIdx.x;
  int l = t & 63;

  if (MODE == 3) {
    if (t < 128) {
      int idx = m0 + t;
      stok[t] = (idx < M) ? btok[e * T_TOK + idx] : 0;
      swt[t] = (idx < M) ? bw[e * T_TOK + idx] : 0.f;
    }
  }

  // staging row assignment: thread t covers rows t>>2 and 64+(t>>2), k-chunk (t&3)*8
  int r1 = t >> 2, r2 = 64 + (t >> 2);
  long arow1, arow2;
  if (MODE == 1) {
    arow1 = btok[e * T_TOK + min(m0 + r1, M - 1)];
    arow2 = btok[e * T_TOK + min(m0 + r2, M - 1)];
  } else if (MODE == 3) {
    arow1 = min(rowbase + m0 + r1, TotalRows - 1);
    arow2 = min(rowbase + m0 + r2, TotalRows - 1);
  } else {
    arow1 = m0 + r1;
    arow2 = m0 + r2;
  }
  const f16* ap1 = A + arow1 * Kd + (t & 3) * 8;
  const f16* ap2 = A + arow2 * Kd + (t & 3) * 8;
  const f16* bp1 = Bp + (long)(n0 + r1) * Kd + (t & 3) * 8;
  const f16* bp2 = Bp + (long)(n0 + r2) * Kd + (t & 3) * 8;
  f16* lA1 = As + t * 8;
  f16* lA2 = As + 2048 + t * 8;
  f16* lB1 = Bs + t * 8;
  f16* lB2 = Bs + 2048 + t * 8;

  f32x4 acc[4][4];
#pragma unroll
  for (int i = 0; i < 4; ++i)
#pragma unroll
    for (int j = 0; j < 4; ++j) acc[i][j] = (f32x4){0.f, 0.f, 0.f, 0.f};

  int wid = t >> 6, wr = wid >> 1, wc = wid & 1;
  int fr = l & 15, fq = (l >> 4) * 8;
  const int aoff = (wr * 64 + fr) * 32 + fq;
  const int boff = (wc * 64 + fr) * 32 + fq;

  for (int k0 = 0; k0 < Kd; k0 += 32) {
    __syncthreads();
    g2l16(ap1, lA1);
    g2l16(ap2, lA2);
    g2l16(bp1, lB1);
    g2l16(bp2, lB2);
    ap1 += 32; ap2 += 32; bp1 += 32; bp2 += 32;
    __syncthreads();
    f16x8 a[4], b[4];
#pragma unroll
    for (int i = 0; i < 4; ++i) {
      a[i] = *(const f16x8*)&As[aoff + i * 16 * 32];
      b[i] = *(const f16x8*)&Bs[boff + i * 16 * 32];
    }
#pragma unroll
    for (int i = 0; i < 4; ++i)
#pragma unroll
      for (int j = 0; j < 4; ++j)
        acc[i][j] = __builtin_amdgcn_mfma_f32_16x16x32_f16(a[i], b[j], acc[i][j], 0, 0, 0);
  }

  // epilogue: D element (row = wr*64+i*16+(l>>4)*4+r, col = n0+wc*64+j*16+(l&15))
#pragma unroll
  for (int i = 0; i < 4; ++i) {
    int mloc_base = wr * 64 + i * 16 + (l >> 4) * 4;
#pragma unroll
    for (int j = 0; j < 4; ++j) {
      int c = n0 + wc * 64 + j * 16 + fr;
#pragma unroll
      for (int r = 0; r < 4; ++r) {
        float v = acc[i][j][r];
        if constexpr (DUAL) {
          float o = __shfl_xor(v, 1);  // partner column (gate<->up)
          int m = m0 + mloc_base + r;
          if ((c & 1) == 0 && m < M) {
            float g = v;
            float hval = g / (1.f + __expf(-g)) * o;  // silu(g)*u
            outB[(long)(rowbase + m) * NoutCols + (c >> 1)] = (f16)hval;
          }
        } else if constexpr (MODE == 2) {
          int m = m0 + mloc_base + r;
          if (m < M) outF[(long)m * NoutCols + c] = v;
        } else {
          int mloc = mloc_base + r;
          int m = m0 + mloc;
          if (m < M) atomicAdd(&outF[(long)stok[mloc] * NoutCols + c], swt[mloc] * v);
        }
      }
    }
  }
}

// ---------------- host ----------------
extern "C" void kernel_launch(void* const* d_in, const int* in_sizes, int n_in,
                              void* d_out, int out_size, void* d_ws, size_t ws_size,
                              hipStream_t stream) {
  const float* x      = (const float*)d_in[0];
  const float* gw     = (const float*)d_in[1];
  const float* gb     = (const float*)d_in[2];
  const float* w_gate = (const float*)d_in[3];
  const float* w_up   = (const float*)d_in[4];
  const float* w_down = (const float*)d_in[5];
  const float* sg     = (const float*)d_in[6];
  const float* su     = (const float*)d_in[7];
  const float* sd     = (const float*)d_in[8];
  float* out = (float*)d_out;
  float* ids_out = out + (size_t)T_TOK * HDIM;

  char* p = (char*)d_ws;
  auto alloc = [&](size_t bytes) {
    char* r = p;
    p += (bytes + 255) & ~(size_t)255;
    return r;
  };
  f16* xb   = (f16*)alloc((size_t)T_TOK * HDIM * 2);
  f16* sgu  = (f16*)alloc((size_t)2 * NSHI * HDIM * 2);        // [4096][2048] interleaved gate/up
  f16* sdt  = (f16*)alloc((size_t)HDIM * NSHI * 2);            // [h][k]
  f16* wgu  = (f16*)alloc((size_t)NEXP * 2 * IDIM * HDIM * 2); // [e][2i+s][h]
  f16* wdt  = (f16*)alloc((size_t)NEXP * HDIM * IDIM * 2);     // [e][h][i]
  f16* shb  = (f16*)alloc((size_t)T_TOK * NSHI * 2);           // shared intermediate
  f16* hb   = (f16*)alloc((size_t)T_TOK * KTOP * IDIM * 2);    // routed intermediate (bucket order)
  int* btok   = (int*)alloc((size_t)NEXP * T_TOK * 4);
  float* bwt  = (float*)alloc((size_t)NEXP * T_TOK * 4);
  int* counts = (int*)alloc(256);
  int* offs   = (int*)alloc(256);
  // total ~602 MiB of d_ws

  k_zero<<<1, 64, 0, stream>>>(counts);
  k_cast_f16<<<(T_TOK * HDIM / 8 + 255) / 256, 256, 0, stream>>>(x, xb, (long)T_TOK * HDIM);

  // weight transpose-casts
  k_tcast<<<dim3(IDIM / 32, HDIM / 32, NEXP), 256, 0, stream>>>(
      w_gate, wgu, HDIM, IDIM, (long)HDIM * IDIM, (long)2 * IDIM * HDIM, 2, 0);
  k_tcast<<<dim3(IDIM / 32, HDIM / 32, NEXP), 256, 0, stream>>>(
      w_up, wgu, HDIM, IDIM, (long)HDIM * IDIM, (long)2 * IDIM * HDIM, 2, 1);
  k_tcast<<<dim3(HDIM / 32, IDIM / 32, NEXP), 256, 0, stream>>>(
      w_down, wdt, IDIM, HDIM, (long)IDIM * HDIM, (long)HDIM * IDIM, 1, 0);
  k_tcast<<<dim3(NSHI / 32, HDIM / 32, 1), 256, 0, stream>>>(sg, sgu, HDIM, NSHI, 0, 0, 2, 0);
  k_tcast<<<dim3(NSHI / 32, HDIM / 32, 1), 256, 0, stream>>>(su, sgu, HDIM, NSHI, 0, 0, 2, 1);
  k_tcast<<<dim3(HDIM / 32, NSHI / 32, 1), 256, 0, stream>>>(sd, sdt, NSHI, HDIM, 0, 0, 1, 0);

  k_router<<<T_TOK / 8, 256, 0, stream>>>(x, gw, gb, counts, btok, bwt, ids_out);
  k_prefix<<<1, 64, 0, stream>>>(counts, offs);

  // shared GEMM1: xb[8192][2048] x sgu(Nb=4096,K=2048) -> shb f16 [8192][2048]
  k_gemm<0><<<dim3(T_TOK / 128, (2 * NSHI) / 128, 1), 256, 0, stream>>>(
      xb, sgu, nullptr, shb, nullptr, nullptr, nullptr, nullptr,
      T_TOK, HDIM, 2 * NSHI, NSHI, T_TOK);
  // expert GEMM1: gathered xb x wgu[e](Nb=2048,K=2048) -> hb f16 rows offsets[e]+m
  k_gemm<1><<<dim3(T_TOK / 128, (2 * IDIM) / 128, NEXP), 256, 0, stream>>>(
      xb, wgu, nullptr, hb, counts, offs, btok, bwt,
      0, HDIM, 2 * IDIM, IDIM, T_TOK);
  // shared GEMM2: shb x sdt(Nb=2048,K=2048) -> out fp32 (plain store, clears poison)
  k_gemm<2><<<dim3(T_TOK / 128, HDIM / 128, 1), 256, 0, stream>>>(
      shb, sdt, out, nullptr, nullptr, nullptr, nullptr, nullptr,
      T_TOK, NSHI, HDIM, HDIM, T_TOK);
  // expert GEMM2: hb x wdt[e](Nb=2048,K=1024) -> weighted atomicAdd into out
  k_gemm<3><<<dim3(T_TOK / 128, HDIM / 128, NEXP), 256, 0, stream>>>(
      hb, wdt, out, nullptr, counts, offs, btok, bwt,
      0, IDIM, HDIM, HDIM, T_TOK * KTOP);
}